// Round 6
// baseline (114.071 us; speedup 1.0000x reference)
//
#include <hip/hip_runtime.h>
#include <math.h>

#define S_LEN 2048
#define D_MODEL 512
#define NIMU 13
#define NCOL 117                 // 13*9
#define CPAD 128                 // padded col stride
#define NKC 8                    // k-split chunks
// Pt[kc][c][s] = Pt[(kc*CPAD + c)*S_LEN + s]
#define KCSTRIDE ((size_t)CPAD * S_LEN)

static __device__ __forceinline__ float softplus_f(float x) {
    return (x > 20.f) ? x : log1pf(expf(x));
}

// osc transform: params -> per-step rotation z and state at dt0
static __device__ __forceinline__ void osc_init(float pk, float pd, float amp, float phi, float dtf,
                                                float& re, float& im, float& zr, float& zi)
{
    const float LOG2E = 1.4426950408889634f;
    const float INV2PI = 0.15915494309189535f;
    float d = sqrtf(pd * pd + 1e-5f);
    float kk = d * d * 0.25f + softplus_f(pk);
    float om = 0.5f * sqrtf(fmaxf(4.f * kk - d * d, 0.f));
    float y = -0.5f * d * LOG2E;       // log2 of decay per step
    float f = om * INV2PI;             // revolutions per step
    float ph = phi * INV2PI;
    float ez = __builtin_amdgcn_exp2f(y);
    zr = ez * __builtin_amdgcn_cosf(f);
    zi = ez * __builtin_amdgcn_sinf(f);
    float er = amp * __builtin_amdgcn_exp2f(dtf * y);
    float r = fmaf(dtf, f, ph); r -= floorf(r);
    re = er * __builtin_amdgcn_cosf(r);
    im = er * __builtin_amdgcn_sinf(r);
}

// ---------------- kernel 1: fused LN stats + projection GEMM + out zero ----------------
// grid (64 row-tiles of 32, 8 k-chunks of 64); block 128 threads (2 waves).
// Each block recomputes full-row LN stats for its 32 rows (bitwise identical across
// the 8 k-chunk blocks of a row-tile), so no separate stats dispatch / global buffer.
__global__ __launch_bounds__(128) void proj_kernel(
    const float* __restrict__ H,
    const float* __restrict__ lnw, const float* __restrict__ lnb,
    const float* __restrict__ W, float* __restrict__ Pt,
    float* __restrict__ out)
{
    __shared__ float Xt[64 * 32];        // [k][row] transposed, LN applied
    __shared__ float Ws[64 * CPAD];      // [k][c], zero-padded cols
    int tid = threadIdx.x;
    int row0 = blockIdx.x * 32;
    int k0 = blockIdx.y * 64;

    // zero-init out (13*2048 = 26624 floats = 6656 float4; 64 by==0 blocks x 104)
    if (blockIdx.y == 0 && tid < 104) {
        ((float4*)out)[blockIdx.x * 104 + tid] = make_float4(0.f, 0.f, 0.f, 0.f);
    }

    // ---- per-row LN stats: 4 threads per row, one-pass sum/sumsq + shfl_xor ----
    int r = tid >> 2;            // row 0..31
    int fq = tid & 3;            // quarter 0..3
    float mu, rstd;
    {
        const float4* hq = (const float4*)(H + (size_t)(row0 + r) * D_MODEL + fq * 128);
        float sum = 0.f, sq = 0.f;
        #pragma unroll 8
        for (int i = 0; i < 32; ++i) {
            float4 v = hq[i];
            sum += v.x + v.y + v.z + v.w;
            sq = fmaf(v.x, v.x, fmaf(v.y, v.y, fmaf(v.z, v.z, fmaf(v.w, v.w, sq))));
        }
        sum += __shfl_xor(sum, 1); sq += __shfl_xor(sq, 1);
        sum += __shfl_xor(sum, 2); sq += __shfl_xor(sq, 2);
        mu = sum * (1.f / 512.f);
        float var = fmaxf(sq * (1.f / 512.f) - mu * mu, 0.f);
        rstd = 1.0f / sqrtf(var + 1e-5f);
    }

    {   // stage W chunk (64 x 117 -> 64 x 128 zero-padded), scalar guarded loads
        #pragma unroll 8
        for (int i = 0; i < 64; ++i) {
            int idx = tid + i * 128;
            int k = idx >> 7;
            int c = idx & 127;
            Ws[idx] = (c < NCOL) ? W[(size_t)(k0 + k) * NCOL + c] : 0.f;
        }
    }
    {   // stage X transposed with LayerNorm (thread r == stats owner of row r)
        int row = row0 + r;
        const float4* H4 = (const float4*)(H + (size_t)row * D_MODEL + k0);
        const float4* w4 = (const float4*)(lnw + k0);
        const float4* b4 = (const float4*)(lnb + k0);
        #pragma unroll
        for (int it = 0; it < 4; ++it) {
            int q = fq + it * 4;
            float4 h = H4[q], wv = w4[q], bv = b4[q];
            Xt[(4 * q + 0) * 32 + r] = (h.x - mu) * rstd * wv.x + bv.x;
            Xt[(4 * q + 1) * 32 + r] = (h.y - mu) * rstd * wv.y + bv.y;
            Xt[(4 * q + 2) * 32 + r] = (h.z - mu) * rstd * wv.z + bv.z;
            Xt[(4 * q + 3) * 32 + r] = (h.w - mu) * rstd * wv.w + bv.w;
        }
    }
    __syncthreads();

    int q8 = tid & 15;     // col group: cols 8*q8..8*q8+7
    int rg = tid >> 4;     // row group: rows 4*rg..4*rg+3
    float acc[4][8];
    #pragma unroll
    for (int a = 0; a < 4; ++a)
        for (int u = 0; u < 8; ++u) acc[a][u] = 0.f;

    #pragma unroll 4
    for (int k = 0; k < 64; ++k) {
        float4 xa = *(float4*)&Xt[k * 32 + 4 * rg];
        float4 w0 = *(float4*)&Ws[k * CPAD + 8 * q8];
        float4 w1 = *(float4*)&Ws[k * CPAD + 8 * q8 + 4];
        float xv[4] = {xa.x, xa.y, xa.z, xa.w};
        float wv[8] = {w0.x, w0.y, w0.z, w0.w, w1.x, w1.y, w1.z, w1.w};
        #pragma unroll
        for (int a = 0; a < 4; ++a)
            #pragma unroll
            for (int u = 0; u < 8; ++u)
                acc[a][u] = fmaf(xv[a], wv[u], acc[a][u]);
    }

    if (q8 < 15) {
        #pragma unroll
        for (int u = 0; u < 8; ++u) {
            int c = 8 * q8 + u;
            if (c < NCOL) {
                float4 v = make_float4(acc[0][u], acc[1][u], acc[2][u], acc[3][u]);
                *(float4*)&Pt[((size_t)blockIdx.y * CPAD + c) * S_LEN + row0 + 4 * rg] = v;
            }
        }
    }
}

// ---------------- kernel 2: inline transform + triangular recurrence + init ----------------
// grid (40, NIMU); block 256 = 4 waves. Wave-tile: 128 sources x 128 dts.
// Group g = sc+tc in [0,16): g+1 tiles, window j in [128g, 128g+255].
// Lane owns sources i0+lane (slot lane+t) and i0+64+lane (slot lane+64+t), both at dt=t.
__global__ __launch_bounds__(256) void main_kernel(
    const float* __restrict__ Pt, const float* __restrict__ bias,
    const float* __restrict__ minp, float* __restrict__ out)
{
    __shared__ float buf[4 * 256];
    int tid = threadIdx.x;
    int lane = tid & 63, w = tid >> 6;
    int m = blockIdx.y;
    int bx = blockIdx.x;

    // decode bx -> (g, sub): group g has ceil((g+1)/4) = (g+4)>>2 blocks
    int g = 0, base = 0;
    #pragma unroll 1
    for (;;) {
        int nb = (g + 4) >> 2;
        if (bx < base + nb) break;
        base += nb; ++g;
    }
    int sub = bx - base;
    int q = sub * 4 + w;               // tile index within group

    float* accW = buf + w * 256;
    accW[lane] = 0.f; accW[lane + 64] = 0.f;
    accW[lane + 128] = 0.f; accW[lane + 192] = 0.f;
    __builtin_amdgcn_wave_barrier();

    if (q <= g) {
        int sc = q, tc = g - q;
        int i0 = sc * 128;
        float dtf = (float)(tc * 128);

        // gather 9 params for sources A = i0+lane, B = i0+64+lane (coalesced b32)
        float pvA[9], pvB[9];
        #pragma unroll
        for (int p = 0; p < 9; ++p) {
            int c = p * 13 + m;
            const float* bp = Pt + (size_t)c * S_LEN + i0 + lane;
            float vA = bias[c], vB = vA;
            #pragma unroll
            for (int kc = 0; kc < NKC; ++kc) {
                vA += bp[kc * KCSTRIDE];
                vB += bp[kc * KCSTRIDE + 64];
            }
            pvA[p] = vA; pvB[p] = vB;
        }

        float reLA, imLA, zrLA, ziLA; osc_init(pvA[0], pvA[1], pvA[4], pvA[6], dtf, reLA, imLA, zrLA, ziLA);
        float reAA, imAA, zrAA, ziAA; osc_init(pvA[2], pvA[3], pvA[5], pvA[7], dtf, reAA, imAA, zrAA, ziAA);
        float reLB, imLB, zrLB, ziLB; osc_init(pvB[0], pvB[1], pvB[4], pvB[6], dtf, reLB, imLB, zrLB, ziLB);
        float reAB, imAB, zrAB, ziAB; osc_init(pvB[2], pvB[3], pvB[5], pvB[7], dtf, reAB, imAB, zrAB, ziAB);

        #pragma unroll 8
        for (int t = 0; t < 128; ++t) {
            // paired slots (lane+t, lane+64+t): stride-1 across lanes, read2/write2-eligible
            float a0 = accW[lane + t];
            float a1 = accW[lane + 64 + t];
            a0 += imLA + imAA;
            a1 += imLB + imAB;
            accW[lane + t] = a0;
            accW[lane + 64 + t] = a1;
            __builtin_amdgcn_wave_barrier();   // pin cross-lane LDS RMW ordering
            float tL = imLA * ziLA; float rL = fmaf(reLA, zrLA, -tL);
            imLA = fmaf(reLA, ziLA, imLA * zrLA); reLA = rL;
            float tA = imAA * ziAA; float rA = fmaf(reAA, zrAA, -tA);
            imAA = fmaf(reAA, ziAA, imAA * zrAA); reAA = rA;
            float tLB = imLB * ziLB; float rLB = fmaf(reLB, zrLB, -tLB);
            imLB = fmaf(reLB, ziLB, imLB * zrLB); reLB = rLB;
            float tAB = imAB * ziAB; float rAB = fmaf(reAB, zrAB, -tAB);
            imAB = fmaf(reAB, ziAB, imAB * zrAB); reAB = rAB;
        }
    }
    __syncthreads();

    // flush: window j in [128g, 128g+256)
    {
        int j = g * 128 + tid;
        if (j < S_LEN) {
            float s = buf[tid] + buf[256 + tid] + buf[512 + tid] + buf[768 + tid];
            if (sub == 0 && tid < 128) {
                // exactly-once init for j in [128g, 128g+128): minp + p8
                int c8 = 8 * 13 + m;
                float v = minp[0] + bias[c8];
                const float* bp = Pt + (size_t)c8 * S_LEN + j;
                #pragma unroll
                for (int kc = 0; kc < NKC; ++kc) v += bp[kc * KCSTRIDE];
                s += v;
            }
            atomicAdd(&out[m * S_LEN + j], s);
        }
    }
}

extern "C" void kernel_launch(void* const* d_in, const int* in_sizes, int n_in,
                              void* d_out, int out_size, void* d_ws, size_t ws_size,
                              hipStream_t stream)
{
    const float* H    = (const float*)d_in[0];
    const float* MINP = (const float*)d_in[1];
    const float* LNW  = (const float*)d_in[2];
    const float* LNB  = (const float*)d_in[3];
    const float* W    = (const float*)d_in[4];
    const float* B    = (const float*)d_in[5];
    float* out = (float*)d_out;

    float* Pt = (float*)d_ws;   // NKC * CPAD * S_LEN * 4 = 8 MB

    proj_kernel<<<dim3(64, 8), 128, 0, stream>>>(H, LNW, LNB, W, Pt, out);
    main_kernel<<<dim3(40, NIMU), 256, 0, stream>>>(Pt, B, MINP, out);
}

// Round 8
// 97.491 us; speedup vs baseline: 1.1701x; 1.1701x over previous
//
#include <hip/hip_runtime.h>
#include <math.h>

#define S_LEN 2048
#define D_MODEL 512
#define NIMU 13
#define NCOL 117                 // 13*9
#define CPAD 128                 // padded col stride
#define NKC 8                    // k-split chunks
// Pt[kc][c][s] = Pt[(kc*CPAD + c)*S_LEN + s]
#define KCSTRIDE ((size_t)CPAD * S_LEN)

static __device__ __forceinline__ float softplus_f(float x) {
    return (x > 20.f) ? x : log1pf(expf(x));
}

// osc transform: params -> per-step rotation z and state at dt0
static __device__ __forceinline__ void osc_init(float pk, float pd, float amp, float phi, float dtf,
                                                float& re, float& im, float& zr, float& zi)
{
    const float LOG2E = 1.4426950408889634f;
    const float INV2PI = 0.15915494309189535f;
    float d = sqrtf(pd * pd + 1e-5f);
    float kk = d * d * 0.25f + softplus_f(pk);
    float om = 0.5f * sqrtf(fmaxf(4.f * kk - d * d, 0.f));
    float y = -0.5f * d * LOG2E;       // log2 of decay per step
    float f = om * INV2PI;             // revolutions per step
    float ph = phi * INV2PI;
    float ez = __builtin_amdgcn_exp2f(y);
    zr = ez * __builtin_amdgcn_cosf(f);
    zi = ez * __builtin_amdgcn_sinf(f);
    float er = amp * __builtin_amdgcn_exp2f(dtf * y);
    float r = fmaf(dtf, f, ph); r -= floorf(r);
    re = er * __builtin_amdgcn_cosf(r);
    im = er * __builtin_amdgcn_sinf(r);
}

// ---------------- kernel 1: LN stats + W pad + out zero ----------------
// 512 blocks x 256. Block bx: rows 4bx..4bx+3 stats; pads W row bx into Wp; zeroes out.
__global__ __launch_bounds__(256) void stats_kernel(const float* __restrict__ H,
                                                    float2* __restrict__ stats,
                                                    const float* __restrict__ W,
                                                    float* __restrict__ Wp,
                                                    float* __restrict__ out) {
    if (blockIdx.x < 104) out[blockIdx.x * 256 + threadIdx.x] = 0.f;   // 104*256 = 26624 = 13*2048
    if (threadIdx.x < CPAD) {
        int c = threadIdx.x;
        Wp[blockIdx.x * CPAD + c] = (c < NCOL) ? W[blockIdx.x * NCOL + c] : 0.f;
    }
    int wave = threadIdx.x >> 6;
    int lane = threadIdx.x & 63;
    int row = blockIdx.x * 4 + wave;
    const float* hr = H + row * D_MODEL;
    float4 a = *(const float4*)&hr[lane * 4];
    float4 b = *(const float4*)&hr[256 + lane * 4];
    float sum = a.x + a.y + a.z + a.w + b.x + b.y + b.z + b.w;
    #pragma unroll
    for (int off = 32; off; off >>= 1) sum += __shfl_down(sum, off);
    sum = __shfl(sum, 0);
    float mu = sum * (1.f / 512.f);
    float vs = 0.f;
    vs += (a.x - mu) * (a.x - mu); vs += (a.y - mu) * (a.y - mu);
    vs += (a.z - mu) * (a.z - mu); vs += (a.w - mu) * (a.w - mu);
    vs += (b.x - mu) * (b.x - mu); vs += (b.y - mu) * (b.y - mu);
    vs += (b.z - mu) * (b.z - mu); vs += (b.w - mu) * (b.w - mu);
    #pragma unroll
    for (int off = 32; off; off >>= 1) vs += __shfl_down(vs, off);
    if (lane == 0) {
        float var = vs * (1.f / 512.f);
        stats[row] = make_float2(mu, 1.0f / sqrtf(var + 1e-5f));
    }
}

// ---------------- kernel 2: projection GEMM -> transposed partials ----------------
// grid (64 row-tiles of 32, 8 k-chunks of 64); block 128 threads.
__global__ __launch_bounds__(128) void proj_kernel(
    const float* __restrict__ H, const float2* __restrict__ stats,
    const float* __restrict__ lnw, const float* __restrict__ lnb,
    const float* __restrict__ Wp, float* __restrict__ Pt)
{
    __shared__ float Xt[64 * 32];        // [k][row] transposed, LN applied
    __shared__ float Ws[64 * CPAD];      // [k][c]
    int tid = threadIdx.x;
    int row0 = blockIdx.x * 32;
    int k0 = blockIdx.y * 64;

    {   // stage W chunk: flat float4 copy (strides match: both 128)
        const float4* Wp4 = (const float4*)(Wp + k0 * CPAD);
        float4* Ws4 = (float4*)Ws;
        #pragma unroll
        for (int i = 0; i < 16; ++i) Ws4[tid + i * 128] = Wp4[tid + i * 128];
    }
    {   // stage X transposed with LayerNorm
        int r = tid >> 2, fq = tid & 3;
        int row = row0 + r;
        float2 st = stats[row];
        const float4* H4 = (const float4*)(H + row * D_MODEL + k0);
        const float4* w4 = (const float4*)(lnw + k0);
        const float4* b4 = (const float4*)(lnb + k0);
        #pragma unroll
        for (int it = 0; it < 4; ++it) {
            int q = fq + it * 4;
            float4 h = H4[q], wv = w4[q], bv = b4[q];
            Xt[(4 * q + 0) * 32 + r] = (h.x - st.x) * st.y * wv.x + bv.x;
            Xt[(4 * q + 1) * 32 + r] = (h.y - st.x) * st.y * wv.y + bv.y;
            Xt[(4 * q + 2) * 32 + r] = (h.z - st.x) * st.y * wv.z + bv.z;
            Xt[(4 * q + 3) * 32 + r] = (h.w - st.x) * st.y * wv.w + bv.w;
        }
    }
    __syncthreads();

    int q8 = tid & 15;     // col group: cols 8*q8..8*q8+7
    int rg = tid >> 4;     // row group: rows 4*rg..4*rg+3
    float acc[4][8];
    #pragma unroll
    for (int a = 0; a < 4; ++a)
        for (int u = 0; u < 8; ++u) acc[a][u] = 0.f;

    #pragma unroll 4
    for (int k = 0; k < 64; ++k) {
        float4 xa = *(float4*)&Xt[k * 32 + 4 * rg];
        float4 w0 = *(float4*)&Ws[k * CPAD + 8 * q8];
        float4 w1 = *(float4*)&Ws[k * CPAD + 8 * q8 + 4];
        float xv[4] = {xa.x, xa.y, xa.z, xa.w};
        float wv[8] = {w0.x, w0.y, w0.z, w0.w, w1.x, w1.y, w1.z, w1.w};
        #pragma unroll
        for (int a = 0; a < 4; ++a)
            #pragma unroll
            for (int u = 0; u < 8; ++u)
                acc[a][u] = fmaf(xv[a], wv[u], acc[a][u]);
    }

    if (q8 < 15) {
        #pragma unroll
        for (int u = 0; u < 8; ++u) {
            int c = 8 * q8 + u;
            if (c < NCOL) {
                float4 v = make_float4(acc[0][u], acc[1][u], acc[2][u], acc[3][u]);
                *(float4*)&Pt[((size_t)blockIdx.y * CPAD + c) * S_LEN + row0 + 4 * rg] = v;
            }
        }
    }
}

// ---------------- kernel 3: inline transform + triangular recurrence + init ----------------
// grid (40, NIMU); block 256 = 4 waves. Wave-tile: 128 sources x 128 dts.
// Group g = sc+tc in [0,16): g+1 tiles, window j in [128g, 128g+255].
// Lane owns sources i0+lane (slot lane+t) and i0+64+lane (slot lane+64+t), both at dt=t.
__global__ __launch_bounds__(256) void main_kernel(
    const float* __restrict__ Pt, const float* __restrict__ bias,
    const float* __restrict__ minp, float* __restrict__ out)
{
    __shared__ float buf[4 * 256];
    int tid = threadIdx.x;
    int lane = tid & 63, w = tid >> 6;
    int m = blockIdx.y;
    int bx = blockIdx.x;

    // decode bx -> (g, sub): group g has ceil((g+1)/4) = (g+4)>>2 blocks
    int g = 0, base = 0;
    #pragma unroll 1
    for (;;) {
        int nb = (g + 4) >> 2;
        if (bx < base + nb) break;
        base += nb; ++g;
    }
    int sub = bx - base;
    int q = sub * 4 + w;               // tile index within group

    float* accW = buf + w * 256;
    accW[lane] = 0.f; accW[lane + 64] = 0.f;
    accW[lane + 128] = 0.f; accW[lane + 192] = 0.f;
    __builtin_amdgcn_wave_barrier();

    if (q <= g) {
        int sc = q, tc = g - q;
        int i0 = sc * 128;
        float dtf = (float)(tc * 128);

        // gather 9 params for sources A = i0+lane, B = i0+64+lane (coalesced b32)
        float pvA[9], pvB[9];
        #pragma unroll
        for (int p = 0; p < 9; ++p) {
            int c = p * 13 + m;
            const float* bp = Pt + (size_t)c * S_LEN + i0 + lane;
            float vA = bias[c], vB = vA;
            #pragma unroll
            for (int kc = 0; kc < NKC; ++kc) {
                vA += bp[kc * KCSTRIDE];
                vB += bp[kc * KCSTRIDE + 64];
            }
            pvA[p] = vA; pvB[p] = vB;
        }

        float reLA, imLA, zrLA, ziLA; osc_init(pvA[0], pvA[1], pvA[4], pvA[6], dtf, reLA, imLA, zrLA, ziLA);
        float reAA, imAA, zrAA, ziAA; osc_init(pvA[2], pvA[3], pvA[5], pvA[7], dtf, reAA, imAA, zrAA, ziAA);
        float reLB, imLB, zrLB, ziLB; osc_init(pvB[0], pvB[1], pvB[4], pvB[6], dtf, reLB, imLB, zrLB, ziLB);
        float reAB, imAB, zrAB, ziAB; osc_init(pvB[2], pvB[3], pvB[5], pvB[7], dtf, reAB, imAB, zrAB, ziAB);

        #pragma unroll 8
        for (int t = 0; t < 128; ++t) {
            // paired slots (lane+t, lane+64+t): stride-1 across lanes, read2/write2-eligible
            float a0 = accW[lane + t];
            float a1 = accW[lane + 64 + t];
            a0 += imLA + imAA;
            a1 += imLB + imAB;
            accW[lane + t] = a0;
            accW[lane + 64 + t] = a1;
            __builtin_amdgcn_wave_barrier();   // pin cross-lane LDS RMW ordering
            float tL = imLA * ziLA; float rL = fmaf(reLA, zrLA, -tL);
            imLA = fmaf(reLA, ziLA, imLA * zrLA); reLA = rL;
            float tA = imAA * ziAA; float rA = fmaf(reAA, zrAA, -tA);
            imAA = fmaf(reAA, ziAA, imAA * zrAA); reAA = rA;
            float tLB = imLB * ziLB; float rLB = fmaf(reLB, zrLB, -tLB);
            imLB = fmaf(reLB, ziLB, imLB * zrLB); reLB = rLB;
            float tAB = imAB * ziAB; float rAB = fmaf(reAB, zrAB, -tAB);
            imAB = fmaf(reAB, ziAB, imAB * zrAB); reAB = rAB;
        }
    }
    __syncthreads();

    // flush: window j in [128g, 128g+256)
    {
        int j = g * 128 + tid;
        if (j < S_LEN) {
            float s = buf[tid] + buf[256 + tid] + buf[512 + tid] + buf[768 + tid];
            if (sub == 0 && tid < 128) {
                // exactly-once init for j in [128g, 128g+128): minp + p8
                int c8 = 8 * 13 + m;
                float v = minp[0] + bias[c8];
                const float* bp = Pt + (size_t)c8 * S_LEN + j;
                #pragma unroll
                for (int kc = 0; kc < NKC; ++kc) v += bp[kc * KCSTRIDE];
                s += v;
            }
            atomicAdd(&out[m * S_LEN + j], s);
        }
    }
}

extern "C" void kernel_launch(void* const* d_in, const int* in_sizes, int n_in,
                              void* d_out, int out_size, void* d_ws, size_t ws_size,
                              hipStream_t stream)
{
    const float* H    = (const float*)d_in[0];
    const float* MINP = (const float*)d_in[1];
    const float* LNW  = (const float*)d_in[2];
    const float* LNB  = (const float*)d_in[3];
    const float* W    = (const float*)d_in[4];
    const float* B    = (const float*)d_in[5];
    float* out = (float*)d_out;

    const size_t PTSZ = (size_t)NKC * CPAD * S_LEN * sizeof(float);  // 8388608
    const size_t STSZ = S_LEN * sizeof(float2);                      // 16384

    char* ws = (char*)d_ws;
    float*  Pt    = (float*)ws;
    float2* stats = (float2*)(ws + PTSZ);
    float*  Wp    = (float*)(ws + PTSZ + STSZ);                      // 512*128*4 = 262144

    stats_kernel<<<512, 256, 0, stream>>>(H, stats, W, Wp, out);
    proj_kernel<<<dim3(64, 8), 128, 0, stream>>>(H, stats, LNW, LNB, Wp, Pt);
    main_kernel<<<dim3(40, NIMU), 256, 0, stream>>>(Pt, B, MINP, out);
}